// Round 17
// baseline (69.908 us; speedup 1.0000x reference)
//
#include <hip/hip_runtime.h>
#include <hip/hip_bf16.h>

// LightPrompt inner_structure_update (dense form), MI355X gfx950.
// Outputs (f32, concat): x[4096,128] | adj[4096,4096] | edge_attr[4096,4096,4]
// Store floor ~49us (337.6 MB @ ~6.9 TB/s fill rate).
//
// R17 = R16 (65.7us) + 2-tile persistent blocks. Diagnosis: 65.7 fits
// C+S+C+S (9+23.7+9+23.7) exactly -- NT stores hold the wave slot until
// drained (endpgm waits vmem), so round-2 blocks can't start while round-1
// stores drain: grid-level serialization. Fix: each block processes TWO
// column tiles sequentially (grid 1024 = exactly one residency round,
// 4 blocks/CU). Tile0's epilogue stores are fire-and-forget; tile1's k-loop
// runs while they drain. acc registers REUSED across tiles (R15's mistake
// was holding acc0 alive through tile1 + deferred epilogue -> reverted).
// Model: [C0 9][C1 9 || S0][S0-tail+S1 ~38] ~= 56us.
// Kept: split-bf16 3-term MFMA (absmax 2.44e-4), NT stores (R13 A/B),
// async-stage prefetch with tile-boundary handoff, rcpf sigmoid, adj via
// Ds full-line transpose (R12), cvt_pk convert (R16), fused x-copy.

typedef float  f32x4  __attribute__((ext_vector_type(4)));
typedef short  bf16x8 __attribute__((ext_vector_type(8)));
typedef unsigned int uint2v __attribute__((ext_vector_type(2)));

static constexpr int Tn = 4096;
static constexpr int Dm = 128;
static constexpr int En = 4;
static constexpr float THRE = 0.55f;
static constexpr float SLOPE = 0.01f;

#define BM 128   // block rows (i)
#define BN 64    // per-tile cols (j); block covers 2 tiles
#define KS 32    // k chunk
#define LDH 40   // u16 per staging row: 80B stride (16B-aligned), 2-way banks
#define LDS_D 68 // f32 per Ds row: 272B stride; writes 2-way, b128 reads min

// Split one f32x4 into hi/lo bf16 pairs, packed as 2x u32 each (cvt_pk path).
__device__ __forceinline__ void split4(const f32x4 v, uint2v& hi, uint2v& lo) {
    const __hip_bfloat162 h0 = __float22bfloat162_rn(float2{v[0], v[1]});
    const __hip_bfloat162 h1 = __float22bfloat162_rn(float2{v[2], v[3]});
    const float2 f0 = __bfloat1622float2(h0);
    const float2 f1 = __bfloat1622float2(h1);
    const __hip_bfloat162 l0 = __float22bfloat162_rn(float2{v[0] - f0.x, v[1] - f0.y});
    const __hip_bfloat162 l1 = __float22bfloat162_rn(float2{v[2] - f1.x, v[3] - f1.y});
    hi[0] = *reinterpret_cast<const unsigned int*>(&h0);
    hi[1] = *reinterpret_cast<const unsigned int*>(&h1);
    lo[0] = *reinterpret_cast<const unsigned int*>(&l0);
    lo[1] = *reinterpret_cast<const unsigned int*>(&l1);
}

__global__ __launch_bounds__(256) void lp_fused(const float* __restrict__ tokens,
                                                const float* __restrict__ edge_token,
                                                float* __restrict__ out) {
    // 34816 B shared: staging arrays (30720 B) alias the front; Ds reuses it
    // after each tile's k-loop (staging dead by then; re-staged next tile).
    __shared__ __align__(16) float smem_f[BM * LDS_D];
    unsigned short* Ah = (unsigned short*)smem_f;     // [BM*LDH]
    unsigned short* Al = Ah + BM * LDH;               // [BM*LDH]
    unsigned short* Bh = Al + BM * LDH;               // [BN*LDH]
    unsigned short* Bl = Bh + BN * LDH;               // [BN*LDH]
    float* Ds = smem_f;                               // [BM][LDS_D]

    const int tid = threadIdx.x;
    const int i0  = blockIdx.y * BM;
    const int j0a = blockIdx.x * (2 * BN);

    // x output = tokens verbatim (131072 float4): first 512 of 1024 blocks.
    const int bid = blockIdx.y * (Tn / (2 * BN)) + blockIdx.x;
    if (bid < 512) {
        reinterpret_cast<f32x4*>(out)[bid * 256 + tid] =
            reinterpret_cast<const f32x4*>(tokens)[bid * 256 + tid];
    }

    const int lane = tid & 63;
    const int w    = tid >> 6;   // wave 0..3
    const int wr   = w >> 1;     // row half (64 rows)
    const int wc   = w & 1;      // col half (32 cols)
    const int lr   = lane & 15;  // frag row/col within 16x16 tile
    const int lk   = lane >> 4;  // k quarter (8 bf16)

    // Per-thread staging coordinates (fixed across kp and tiles).
    int arw[4], ac4[4], brw[2], bc4[2];
#pragma unroll
    for (int p = 0; p < 4; ++p) {
        const int f = (p << 8) + tid;
        arw[p] = f >> 3;
        ac4[p] = (f & 7) << 2;
    }
#pragma unroll
    for (int p = 0; p < 2; ++p) {
        const int f = (p << 8) + tid;
        brw[p] = f >> 3;
        bc4[p] = (f & 7) << 2;
    }

    const float e0 = edge_token[0];
    const float e1 = edge_token[1];
    const float e2 = edge_token[2];
    const float e3 = edge_token[3];

    float* __restrict__ adj  = out + (size_t)Tn * Dm;
    float* __restrict__ attr = adj + (size_t)Tn * Tn;

    // Prefetch registers (tile0, kp0).
    f32x4 pa[4], pb[2];
#pragma unroll
    for (int p = 0; p < 4; ++p)
        pa[p] = *reinterpret_cast<const f32x4*>(
            tokens + (size_t)(i0 + arw[p]) * Dm + ac4[p]);
#pragma unroll
    for (int p = 0; p < 2; ++p)
        pb[p] = *reinterpret_cast<const f32x4*>(
            tokens + (size_t)(j0a + brw[p]) * Dm + bc4[p]);

#pragma unroll 1
    for (int t = 0; t < 2; ++t) {
        const int j0 = j0a + t * BN;

        f32x4 acc[4][2];
#pragma unroll
        for (int rt = 0; rt < 4; ++rt)
#pragma unroll
            for (int ct = 0; ct < 2; ++ct) acc[rt][ct] = (f32x4)(0.0f);

#pragma unroll 1
        for (int kp = 0; kp < Dm / KS; ++kp) {
            // Convert (cvt_pk) + LDS write; the trailing barrier of the
            // previous phase ordered these writes after all prior LDS reads.
#pragma unroll
            for (int p = 0; p < 4; ++p) {
                uint2v hi, lo;
                split4(pa[p], hi, lo);
                *reinterpret_cast<uint2v*>(&Ah[arw[p] * LDH + ac4[p]]) = hi;
                *reinterpret_cast<uint2v*>(&Al[arw[p] * LDH + ac4[p]]) = lo;
            }
#pragma unroll
            for (int p = 0; p < 2; ++p) {
                uint2v hi, lo;
                split4(pb[p], hi, lo);
                *reinterpret_cast<uint2v*>(&Bh[brw[p] * LDH + bc4[p]]) = hi;
                *reinterpret_cast<uint2v*>(&Bl[brw[p] * LDH + bc4[p]]) = lo;
            }
            // Prefetch: next kp of this tile, or kp0 of the next tile.
            if (kp < Dm / KS - 1) {
                const int kb = (kp + 1) * KS;
#pragma unroll
                for (int p = 0; p < 4; ++p)
                    pa[p] = *reinterpret_cast<const f32x4*>(
                        tokens + (size_t)(i0 + arw[p]) * Dm + kb + ac4[p]);
#pragma unroll
                for (int p = 0; p < 2; ++p)
                    pb[p] = *reinterpret_cast<const f32x4*>(
                        tokens + (size_t)(j0 + brw[p]) * Dm + kb + bc4[p]);
            } else if (t == 0) {
#pragma unroll
                for (int p = 0; p < 4; ++p)
                    pa[p] = *reinterpret_cast<const f32x4*>(
                        tokens + (size_t)(i0 + arw[p]) * Dm + ac4[p]);
#pragma unroll
                for (int p = 0; p < 2; ++p)
                    pb[p] = *reinterpret_cast<const f32x4*>(
                        tokens + (size_t)(j0a + BN + brw[p]) * Dm + bc4[p]);
            }
            __syncthreads();

            // Fragments: lane lr = tile row/col, lk*8 = k offset (b128 reads).
            bf16x8 afh[4], afl[4], bfh[2], bfl[2];
#pragma unroll
            for (int rt = 0; rt < 4; ++rt) {
                const int row = (wr << 6) + (rt << 4) + lr;
                afh[rt] = *reinterpret_cast<const bf16x8*>(&Ah[row * LDH + (lk << 3)]);
                afl[rt] = *reinterpret_cast<const bf16x8*>(&Al[row * LDH + (lk << 3)]);
            }
#pragma unroll
            for (int ct = 0; ct < 2; ++ct) {
                const int col = (wc << 5) + (ct << 4) + lr;
                bfh[ct] = *reinterpret_cast<const bf16x8*>(&Bh[col * LDH + (lk << 3)]);
                bfl[ct] = *reinterpret_cast<const bf16x8*>(&Bl[col * LDH + (lk << 3)]);
            }
#pragma unroll
            for (int rt = 0; rt < 4; ++rt)
#pragma unroll
                for (int ct = 0; ct < 2; ++ct) {
                    acc[rt][ct] = __builtin_amdgcn_mfma_f32_16x16x32_bf16(
                        afh[rt], bfh[ct], acc[rt][ct], 0, 0, 0);
                    acc[rt][ct] = __builtin_amdgcn_mfma_f32_16x16x32_bf16(
                        afh[rt], bfl[ct], acc[rt][ct], 0, 0, 0);
                    acc[rt][ct] = __builtin_amdgcn_mfma_f32_16x16x32_bf16(
                        afl[rt], bfh[ct], acc[rt][ct], 0, 0, 0);
                }
            __syncthreads();   // staging LDS dead -> Ds reuse safe
        }

        // Epilogue: attr direct NT (fire-and-forget; drains under the next
        // tile's k-loop); sim*m staged into Ds for the adj transpose.
        // C/D layout (m89-verified): col = lane&15, row = (lane>>4)*4 + reg.
#pragma unroll
        for (int rt = 0; rt < 4; ++rt) {
#pragma unroll
            for (int ct = 0; ct < 2; ++ct) {
                const f32x4 dv = acc[rt][ct];
                const int jl = (wc << 5) + (ct << 4) + lr;
                const int j = j0 + jl;
#pragma unroll
                for (int reg = 0; reg < 4; ++reg) {
                    const int il = (wr << 6) + (rt << 4) + (lk << 2) + reg;
                    const float d = dv[reg];
                    const float sim = __builtin_amdgcn_rcpf(1.0f + __expf(-d));
                    const float m = (sim >= THRE) ? 1.0f : 0.0f;
                    Ds[il * LDS_D + jl] = sim * m;
                    f32x4 at;
                    float v;
                    v = d * e0; at.x = (v > 0.0f ? v : SLOPE * v) * m;
                    v = d * e1; at.y = (v > 0.0f ? v : SLOPE * v) * m;
                    v = d * e2; at.z = (v > 0.0f ? v : SLOPE * v) * m;
                    v = d * e3; at.w = (v > 0.0f ? v : SLOPE * v) * m;
                    __builtin_nontemporal_store(at,
                        reinterpret_cast<f32x4*>(attr + ((size_t)(i0 + il) * Tn + j) * En));
                }
            }
        }
        __syncthreads();

        // adj from Ds, row-major: per wave-instr 4 rows x 256B (full lines).
        const int c4 = lr << 2;
#pragma unroll
        for (int s = 0; s < 8; ++s) {
            const int row = (w << 5) + (s << 2) + lk;
            const f32x4 v = *reinterpret_cast<const f32x4*>(&Ds[row * LDS_D + c4]);
            __builtin_nontemporal_store(v,
                reinterpret_cast<f32x4*>(adj + (size_t)(i0 + row) * Tn + j0 + c4));
        }
        __syncthreads();   // Ds dead before the next tile's staging writes
    }
}

extern "C" void kernel_launch(void* const* d_in, const int* in_sizes, int n_in,
                              void* d_out, int out_size, void* d_ws, size_t ws_size,
                              hipStream_t stream) {
    const float* tokens     = (const float*)d_in[0];  // [1,4096,128] f32
    const float* edge_token = (const float*)d_in[1];  // [1,4] f32
    float* out = (float*)d_out;

    hipLaunchKernelGGL(lp_fused, dim3(Tn / (2 * BN), Tn / BM), dim3(256), 0, stream,
                       tokens, edge_token, out);
}

// Round 18
// 65.665 us; speedup vs baseline: 1.0646x; 1.0646x over previous
//
#include <hip/hip_runtime.h>
#include <hip/hip_bf16.h>

// LightPrompt inner_structure_update (dense form), MI355X gfx950.
// Outputs (f32, concat): x[4096,128] | adj[4096,4096] | edge_attr[4096,4096,4]
// Store floor ~49us (337.6 MB @ ~6.9 TB/s fill rate).
//
// R18 = exact revert to R16 (65.65us, best; reproduced 65.7 twice as R14).
// R15/R17 falsified the persistent-block round-overlap theory twice (-4/-5us
// each): rounds already overlap in this structure; forcing one residency
// round only adds junction barriers. Final ledger of proven levers:
//  - split-bf16 3-term MFMA dot ah*bh+ah*bl+al*bh (R10: 91.7->74.1; al*bl
//    dropped ~1e-7, absmax 2.44e-4 vs 1.23e-2 threshold)
//  - adj via LDS Ds transpose -> full-line NT stores (R12: 74.1->66.6)
//  - NT > plain stores (R13 A/B: 66.6 vs 68.9)
//  - async-stage reg prefetch + rcpf sigmoid (R14: -1us)
//  - cvt_pk convert via HIP bf16 API (R16: null but kept, fewer VALU ops)
// Estimated structural floor ~63us (49 store + ~9 lead-in compute + ~5
// barrier/junction residue); this kernel is within ~4% of it.

typedef float  f32x4  __attribute__((ext_vector_type(4)));
typedef short  bf16x8 __attribute__((ext_vector_type(8)));
typedef unsigned int uint2v __attribute__((ext_vector_type(2)));

static constexpr int Tn = 4096;
static constexpr int Dm = 128;
static constexpr int En = 4;
static constexpr float THRE = 0.55f;
static constexpr float SLOPE = 0.01f;

#define BM 128   // block rows (i)
#define BN 64    // block cols (j)
#define KS 32    // k chunk
#define LDH 40   // u16 per staging row: 80B stride (16B-aligned), 2-way banks
#define LDS_D 68 // f32 per Ds row: 272B stride; writes 2-way, b128 reads min

// Split one f32x4 into hi/lo bf16 pairs, packed as 2x u32 each (cvt_pk path).
__device__ __forceinline__ void split4(const f32x4 v, uint2v& hi, uint2v& lo) {
    const __hip_bfloat162 h0 = __float22bfloat162_rn(float2{v[0], v[1]});
    const __hip_bfloat162 h1 = __float22bfloat162_rn(float2{v[2], v[3]});
    const float2 f0 = __bfloat1622float2(h0);
    const float2 f1 = __bfloat1622float2(h1);
    const __hip_bfloat162 l0 = __float22bfloat162_rn(float2{v[0] - f0.x, v[1] - f0.y});
    const __hip_bfloat162 l1 = __float22bfloat162_rn(float2{v[2] - f1.x, v[3] - f1.y});
    hi[0] = *reinterpret_cast<const unsigned int*>(&h0);
    hi[1] = *reinterpret_cast<const unsigned int*>(&h1);
    lo[0] = *reinterpret_cast<const unsigned int*>(&l0);
    lo[1] = *reinterpret_cast<const unsigned int*>(&l1);
}

__global__ __launch_bounds__(256) void lp_fused(const float* __restrict__ tokens,
                                                const float* __restrict__ edge_token,
                                                float* __restrict__ out) {
    // 34816 B shared: staging arrays (30720 B) alias the front; Ds reuses it
    // after the k-loop's final barrier (staging dead by then).
    __shared__ __align__(16) float smem_f[BM * LDS_D];
    unsigned short* Ah = (unsigned short*)smem_f;     // [BM*LDH]
    unsigned short* Al = Ah + BM * LDH;               // [BM*LDH]
    unsigned short* Bh = Al + BM * LDH;               // [BN*LDH]
    unsigned short* Bl = Bh + BN * LDH;               // [BN*LDH]
    float* Ds = smem_f;                               // [BM][LDS_D]

    const int tid = threadIdx.x;
    const int i0 = blockIdx.y * BM;
    const int j0 = blockIdx.x * BN;

    // x output = tokens verbatim (131072 float4): first 512 of 2048 blocks.
    const int bid = blockIdx.y * (Tn / BN) + blockIdx.x;
    if (bid < 512) {
        reinterpret_cast<f32x4*>(out)[bid * 256 + tid] =
            reinterpret_cast<const f32x4*>(tokens)[bid * 256 + tid];
    }

    const int lane = tid & 63;
    const int w    = tid >> 6;   // wave 0..3
    const int wr   = w >> 1;     // row half (64 rows)
    const int wc   = w & 1;      // col half (32 cols)
    const int lr   = lane & 15;  // frag row/col within 16x16 tile
    const int lk   = lane >> 4;  // k quarter (8 bf16)

    // Per-thread staging coordinates (fixed across kp).
    int arw[4], ac4[4], brw[2], bc4[2];
#pragma unroll
    for (int p = 0; p < 4; ++p) {
        const int f = (p << 8) + tid;
        arw[p] = f >> 3;
        ac4[p] = (f & 7) << 2;
    }
#pragma unroll
    for (int p = 0; p < 2; ++p) {
        const int f = (p << 8) + tid;
        brw[p] = f >> 3;
        bc4[p] = (f & 7) << 2;
    }

    f32x4 acc[4][2];
#pragma unroll
    for (int rt = 0; rt < 4; ++rt)
#pragma unroll
        for (int ct = 0; ct < 2; ++ct) acc[rt][ct] = (f32x4)(0.0f);

    // Prefetch registers: kp's staging data loaded one iteration ahead.
    f32x4 pa[4], pb[2];
#pragma unroll
    for (int p = 0; p < 4; ++p)
        pa[p] = *reinterpret_cast<const f32x4*>(
            tokens + (size_t)(i0 + arw[p]) * Dm + ac4[p]);
#pragma unroll
    for (int p = 0; p < 2; ++p)
        pb[p] = *reinterpret_cast<const f32x4*>(
            tokens + (size_t)(j0 + brw[p]) * Dm + bc4[p]);

#pragma unroll 1
    for (int kp = 0; kp < Dm / KS; ++kp) {
        // Convert (cvt_pk) + LDS write; prev iter's trailing barrier ordered
        // these writes after all prior LDS reads.
#pragma unroll
        for (int p = 0; p < 4; ++p) {
            uint2v hi, lo;
            split4(pa[p], hi, lo);
            *reinterpret_cast<uint2v*>(&Ah[arw[p] * LDH + ac4[p]]) = hi;
            *reinterpret_cast<uint2v*>(&Al[arw[p] * LDH + ac4[p]]) = lo;
        }
#pragma unroll
        for (int p = 0; p < 2; ++p) {
            uint2v hi, lo;
            split4(pb[p], hi, lo);
            *reinterpret_cast<uint2v*>(&Bh[brw[p] * LDH + bc4[p]]) = hi;
            *reinterpret_cast<uint2v*>(&Bl[brw[p] * LDH + bc4[p]]) = lo;
        }
        // Issue next kp's loads now: latency hides under barrier+frags+MFMA.
        if (kp < Dm / KS - 1) {
            const int kb = (kp + 1) * KS;
#pragma unroll
            for (int p = 0; p < 4; ++p)
                pa[p] = *reinterpret_cast<const f32x4*>(
                    tokens + (size_t)(i0 + arw[p]) * Dm + kb + ac4[p]);
#pragma unroll
            for (int p = 0; p < 2; ++p)
                pb[p] = *reinterpret_cast<const f32x4*>(
                    tokens + (size_t)(j0 + brw[p]) * Dm + kb + bc4[p]);
        }
        __syncthreads();

        // Fragments: lane lr = tile row/col, lk*8 = k offset (16B b128 reads).
        bf16x8 afh[4], afl[4], bfh[2], bfl[2];
#pragma unroll
        for (int rt = 0; rt < 4; ++rt) {
            const int row = (wr << 6) + (rt << 4) + lr;
            afh[rt] = *reinterpret_cast<const bf16x8*>(&Ah[row * LDH + (lk << 3)]);
            afl[rt] = *reinterpret_cast<const bf16x8*>(&Al[row * LDH + (lk << 3)]);
        }
#pragma unroll
        for (int ct = 0; ct < 2; ++ct) {
            const int col = (wc << 5) + (ct << 4) + lr;
            bfh[ct] = *reinterpret_cast<const bf16x8*>(&Bh[col * LDH + (lk << 3)]);
            bfl[ct] = *reinterpret_cast<const bf16x8*>(&Bl[col * LDH + (lk << 3)]);
        }
#pragma unroll
        for (int rt = 0; rt < 4; ++rt)
#pragma unroll
            for (int ct = 0; ct < 2; ++ct) {
                acc[rt][ct] = __builtin_amdgcn_mfma_f32_16x16x32_bf16(
                    afh[rt], bfh[ct], acc[rt][ct], 0, 0, 0);
                acc[rt][ct] = __builtin_amdgcn_mfma_f32_16x16x32_bf16(
                    afh[rt], bfl[ct], acc[rt][ct], 0, 0, 0);
                acc[rt][ct] = __builtin_amdgcn_mfma_f32_16x16x32_bf16(
                    afl[rt], bfh[ct], acc[rt][ct], 0, 0, 0);
            }
        __syncthreads();   // also makes staging LDS dead -> Ds reuse safe
    }

    const float e0 = edge_token[0];
    const float e1 = edge_token[1];
    const float e2 = edge_token[2];
    const float e3 = edge_token[3];

    float* __restrict__ adj  = out + (size_t)Tn * Dm;
    float* __restrict__ attr = adj + (size_t)Tn * Tn;

    // C/D layout (m89-verified): col = lane&15, row = (lane>>4)*4 + reg.
    // attr direct NT (256B contiguous per 4-store cluster); sim*m into Ds.
#pragma unroll
    for (int rt = 0; rt < 4; ++rt) {
#pragma unroll
        for (int ct = 0; ct < 2; ++ct) {
            const f32x4 dv = acc[rt][ct];
            const int jl = (wc << 5) + (ct << 4) + lr;
            const int j = j0 + jl;
#pragma unroll
            for (int reg = 0; reg < 4; ++reg) {
                const int il = (wr << 6) + (rt << 4) + (lk << 2) + reg;
                const float d = dv[reg];
                const float sim = __builtin_amdgcn_rcpf(1.0f + __expf(-d));
                const float m = (sim >= THRE) ? 1.0f : 0.0f;
                Ds[il * LDS_D + jl] = sim * m;
                f32x4 at;
                float v;
                v = d * e0; at.x = (v > 0.0f ? v : SLOPE * v) * m;
                v = d * e1; at.y = (v > 0.0f ? v : SLOPE * v) * m;
                v = d * e2; at.z = (v > 0.0f ? v : SLOPE * v) * m;
                v = d * e3; at.w = (v > 0.0f ? v : SLOPE * v) * m;
                __builtin_nontemporal_store(at,
                    reinterpret_cast<f32x4*>(attr + ((size_t)(i0 + il) * Tn + j) * En));
            }
        }
    }
    __syncthreads();

    // adj from Ds, row-major: per wave-instr 4 rows x 256B (2 full lines).
    const int c4 = lr << 2;
#pragma unroll
    for (int s = 0; s < 8; ++s) {
        const int row = (w << 5) + (s << 2) + lk;
        const f32x4 v = *reinterpret_cast<const f32x4*>(&Ds[row * LDS_D + c4]);
        __builtin_nontemporal_store(v,
            reinterpret_cast<f32x4*>(adj + (size_t)(i0 + row) * Tn + j0 + c4));
    }
}

extern "C" void kernel_launch(void* const* d_in, const int* in_sizes, int n_in,
                              void* d_out, int out_size, void* d_ws, size_t ws_size,
                              hipStream_t stream) {
    const float* tokens     = (const float*)d_in[0];  // [1,4096,128] f32
    const float* edge_token = (const float*)d_in[1];  // [1,4] f32
    float* out = (float*)d_out;

    hipLaunchKernelGGL(lp_fused, dim3(Tn / BN, Tn / BM), dim3(256), 0, stream,
                       tokens, edge_token, out);
}